// Round 1
// baseline (151.021 us; speedup 1.0000x reference)
//
#include <hip/hip_runtime.h>
#include <hip/hip_bf16.h>

#define B_    2
#define H_    16
#define HKV_  4
#define SQ_   1024
#define SP_   1024
#define SK_   2048
#define D_    128
#define QBLK  64
#define KVBLK 64
#define NT    4
#define KPAD  136   // K lds row stride (bf16 elems): 272B, 16B-aligned, 2-way banks
#define VPAD  72    // Vt lds row stride: 144B, 16B-aligned
#define PPAD  72

typedef __attribute__((ext_vector_type(8))) __bf16 bf16x8;
typedef __attribute__((ext_vector_type(4))) __bf16 bf16x4;
typedef __attribute__((ext_vector_type(2))) __bf16 bf16x2;
typedef __attribute__((ext_vector_type(4))) float  f32x4;

__device__ inline __bf16 f2bf(float f) { return (__bf16)f; }

__global__ __launch_bounds__(256)
void attn_fwd_kernel(const float* __restrict__ Q, const float* __restrict__ Kin,
                     const float* __restrict__ Vin, const float* __restrict__ PK,
                     const float* __restrict__ PV, float* __restrict__ Out)
{
    __shared__ __bf16 Klds[KVBLK][KPAD];
    __shared__ __bf16 Vlds[D_][VPAD];     // transposed: [d][k]
    __shared__ __bf16 Plds[4][16][PPAD];  // per-wave P bounce

    const int tid  = threadIdx.x;
    const int lane = tid & 63;
    const int w    = tid >> 6;
    const int lr   = lane & 15;   // MFMA "row/col lane"
    const int lg   = lane >> 4;   // 4-lane-group id 0..3

    const int qt = blockIdx.x;
    const int h  = blockIdx.y;
    const int b  = blockIdx.z;

    const int q0w = qt * QBLK + w * 16;

    const float scale_l2e = 0.08838834764831845f * 1.4426950408889634f; // 1/sqrt(128)*log2(e)

    // ---- Q fragments in registers (16 rows x 128 d per wave) ----
    bf16x8 qf[4];
    {
        const float* qsrc = Q + (((size_t)b*H_ + h)*SQ_ + q0w + lr)*(size_t)D_ + lg*8;
        #pragma unroll
        for (int c = 0; c < 4; ++c) {
            float4 a0 = *(const float4*)(qsrc + c*32);
            float4 a1 = *(const float4*)(qsrc + c*32 + 4);
            bf16x8 f;
            f[0]=f2bf(a0.x); f[1]=f2bf(a0.y); f[2]=f2bf(a0.z); f[3]=f2bf(a0.w);
            f[4]=f2bf(a1.x); f[5]=f2bf(a1.y); f[6]=f2bf(a1.z); f[7]=f2bf(a1.w);
            qf[c] = f;
        }
    }

    f32x4 o[8];
    #pragma unroll
    for (int i = 0; i < 8; ++i) o[i] = (f32x4){0.f,0.f,0.f,0.f};
    float m_r[4], l_r[4];
    #pragma unroll
    for (int r = 0; r < 4; ++r) { m_r[r] = -1e30f; l_r[r] = 0.f; }

    const int ntiles = qt + 17;   // keys up to q0b+63+1024

    for (int kt = 0; kt < ntiles; ++kt) {
        const int k0 = kt * KVBLK;
        __syncthreads();   // previous tile's compute done before overwrite

        // ---- stage K tile: 64 x 128, fp32 -> bf16 ----
        {
            const float* ksrc = (k0 < SP_)
                ? PK  + (((size_t)b*HKV_ + (h>>2))*SP_ + k0)*(size_t)D_
                : Kin + (((size_t)b*H_   + h     )*SQ_ + (k0 - SP_))*(size_t)D_;
            #pragma unroll
            for (int i = 0; i < 8; ++i) {
                int idx = tid + i*256;
                int row = idx >> 5;
                int c4  = idx & 31;
                float4 v = *(const float4*)(ksrc + row*D_ + c4*4);
                bf16x4 sv; sv[0]=f2bf(v.x); sv[1]=f2bf(v.y); sv[2]=f2bf(v.z); sv[3]=f2bf(v.w);
                *(bf16x4*)&Klds[row][c4*4] = sv;
            }
            // ---- stage V tile transposed: Vlds[d][k], 2k x 4d blocks ----
            const float* vsrc = (k0 < SP_)
                ? PV  + (((size_t)b*HKV_ + (h>>2))*SP_ + k0)*(size_t)D_
                : Vin + (((size_t)b*H_   + h     )*SQ_ + (k0 - SP_))*(size_t)D_;
            #pragma unroll
            for (int i = 0; i < 4; ++i) {
                int blk = tid + i*256;       // 0..1023
                int bd  = blk & 31;          // d-quad
                int bk  = blk >> 5;          // k-pair
                float4 v0 = *(const float4*)(vsrc + (2*bk  )*D_ + bd*4);
                float4 v1 = *(const float4*)(vsrc + (2*bk+1)*D_ + bd*4);
                float a0[4] = {v0.x,v0.y,v0.z,v0.w};
                float a1[4] = {v1.x,v1.y,v1.z,v1.w};
                #pragma unroll
                for (int jj = 0; jj < 4; ++jj) {
                    int j = (jj + bd) & 3;   // permute write order -> ~4-way banks
                    bf16x2 p2; p2[0]=f2bf(a0[j]); p2[1]=f2bf(a1[j]);
                    *(bf16x2*)&Vlds[4*bd + j][2*bk] = p2;
                }
            }
        }
        __syncthreads();

        // fully-masked tile for this wave? (keep barriers above/below uniform)
        if (k0 > q0w + 15 + SP_) continue;

        // ---- QK^T: S(16q x 64k) ----
        f32x4 s[NT];
        #pragma unroll
        for (int n = 0; n < NT; ++n) s[n] = (f32x4){0.f,0.f,0.f,0.f};
        #pragma unroll
        for (int n = 0; n < NT; ++n) {
            #pragma unroll
            for (int c = 0; c < 4; ++c) {
                bf16x8 kf = *(const bf16x8*)&Klds[n*16 + lr][c*32 + lg*8];
                s[n] = __builtin_amdgcn_mfma_f32_16x16x32_bf16(qf[c], kf, s[n], 0, 0, 0);
            }
        }

        // ---- scale + causal mask (log2 domain) ----
        const bool needmask = (k0 + KVBLK - 1) > (q0w + SP_);
        float s2[NT][4];
        #pragma unroll
        for (int n = 0; n < NT; ++n) {
            #pragma unroll
            for (int r = 0; r < 4; ++r) {
                float v = s[n][r] * scale_l2e;
                if (needmask) {
                    int kg = k0 + n*16 + lr;
                    int qg = q0w + lg*4 + r;
                    if (kg > qg + SP_) v = -1e30f;
                }
                s2[n][r] = v;
            }
        }

        // ---- online softmax: per-row max/sum via width-16 shfl_xor ----
        #pragma unroll
        for (int r = 0; r < 4; ++r) {
            float mx = fmaxf(fmaxf(s2[0][r], s2[1][r]), fmaxf(s2[2][r], s2[3][r]));
            mx = fmaxf(mx, __shfl_xor(mx, 1, 16));
            mx = fmaxf(mx, __shfl_xor(mx, 2, 16));
            mx = fmaxf(mx, __shfl_xor(mx, 4, 16));
            mx = fmaxf(mx, __shfl_xor(mx, 8, 16));
            float mnew  = fmaxf(m_r[r], mx);
            float alpha = exp2f(m_r[r] - mnew);
            m_r[r] = mnew;
            float psum = 0.f;
            #pragma unroll
            for (int n = 0; n < NT; ++n) {
                float p = exp2f(s2[n][r] - mnew);
                s2[n][r] = p;
                psum += p;
            }
            psum += __shfl_xor(psum, 1, 16);
            psum += __shfl_xor(psum, 2, 16);
            psum += __shfl_xor(psum, 4, 16);
            psum += __shfl_xor(psum, 8, 16);
            l_r[r] = l_r[r]*alpha + psum;
            #pragma unroll
            for (int dt = 0; dt < 8; ++dt) o[dt][r] *= alpha;
        }

        // ---- P -> per-wave LDS bounce (re-layout for PV A-operand) ----
        #pragma unroll
        for (int n = 0; n < NT; ++n)
            #pragma unroll
            for (int r = 0; r < 4; ++r)
                Plds[w][lg*4 + r][n*16 + lr] = f2bf(s2[n][r]);

        // ---- PV: O(16q x 128d) += P(16x64) * V(64x128) ----
        #pragma unroll
        for (int kk = 0; kk < 2; ++kk) {
            bf16x8 pa = *(const bf16x8*)&Plds[w][lr][kk*32 + lg*8];
            #pragma unroll
            for (int dt = 0; dt < 8; ++dt) {
                bf16x8 vf = *(const bf16x8*)&Vlds[dt*16 + lr][kk*32 + lg*8];
                o[dt] = __builtin_amdgcn_mfma_f32_16x16x32_bf16(pa, vf, o[dt], 0, 0, 0);
            }
        }
    }

    // ---- epilogue: divide by softmax denom, write fp32 ----
    float* obase = Out + (((size_t)b*H_ + h)*SQ_ + q0w)*(size_t)D_;
    #pragma unroll
    for (int r = 0; r < 4; ++r) {
        float inv = 1.0f / l_r[r];
        int row = lg*4 + r;
        #pragma unroll
        for (int dt = 0; dt < 8; ++dt)
            obase[(size_t)row*D_ + dt*16 + lr] = o[dt][r] * inv;
    }
}

// present_key[b,g] = concat(past_key[b,g], K[b,4g]); same for value.
__global__ __launch_bounds__(256)
void copy_present_kernel(const float* __restrict__ Kin, const float* __restrict__ Vin,
                         const float* __restrict__ PK,  const float* __restrict__ PV,
                         float* __restrict__ opk, float* __restrict__ opv)
{
    const int n4 = B_*HKV_*SK_*(D_/4);         // 524288 float4 per output
    int idx = blockIdx.x*256 + threadIdx.x;    // 0 .. 2*n4-1
    bool isV = false;
    if (idx >= n4) { idx -= n4; isV = true; }
    int d4 = idx & 31;
    int s  = (idx >> 5) & (SK_-1);
    int bg = idx >> 16;                        // b*4+g
    int bb = bg >> 2, g = bg & 3;
    const float* srcp;
    if (s < SP_)
        srcp = (isV ? PV : PK) + (((size_t)bg)*SP_ + s)*(size_t)D_ + d4*4;
    else
        srcp = (isV ? Vin : Kin) + (((size_t)(bb*H_ + 4*g))*SQ_ + (s - SP_))*(size_t)D_ + d4*4;
    float4 v = *(const float4*)srcp;
    float* dstp = (isV ? opv : opk) + (size_t)idx*4;
    *(float4*)dstp = v;
}

extern "C" void kernel_launch(void* const* d_in, const int* in_sizes, int n_in,
                              void* d_out, int out_size, void* d_ws, size_t ws_size,
                              hipStream_t stream) {
    const float* Q   = (const float*)d_in[0];
    const float* K   = (const float*)d_in[1];
    const float* V   = (const float*)d_in[2];
    const float* PK  = (const float*)d_in[3];
    const float* PV  = (const float*)d_in[4];
    float* out = (float*)d_out;
    float* opk = out + (size_t)B_*H_*SQ_*D_;           // 4,194,304
    float* opv = opk + (size_t)B_*HKV_*SK_*D_;         // +2,097,152

    dim3 agrid(SQ_/QBLK, H_, B_);
    attn_fwd_kernel<<<agrid, 256, 0, stream>>>(Q, K, V, PK, PV, out);

    int copyblocks = (2 * B_*HKV_*SK_*(D_/4)) / 256;   // 4096
    copy_present_kernel<<<copyblocks, 256, 0, stream>>>(K, V, PK, PV, opk, opv);
}

// Round 2
// 98.933 us; speedup vs baseline: 1.5265x; 1.5265x over previous
//
#include <hip/hip_runtime.h>
#include <hip/hip_bf16.h>

#define B_    2
#define H_    16
#define HKV_  4
#define SQ_   1024
#define SP_   1024
#define SK_   2048
#define D_    128
#define QBLK  64
#define KVBLK 64

typedef __attribute__((ext_vector_type(8))) __bf16 bf16x8;
typedef __attribute__((ext_vector_type(4))) __bf16 bf16x4;
typedef __attribute__((ext_vector_type(4))) float  f32x4;

__device__ inline __bf16 f2bf(float f) { return (__bf16)f; }

__global__ __launch_bounds__(256, 2)
void attn_fwd_kernel(const float* __restrict__ Q, const float* __restrict__ Kin,
                     const float* __restrict__ Vin, const float* __restrict__ PK,
                     const float* __restrict__ PV, float* __restrict__ Out)
{
    // Linear layouts + XOR swizzle (byte ^= (row&7)<<4) on write AND read.
    __shared__ __align__(16) __bf16 Klds[KVBLK * D_];    // [64 k][128 d], 16 KB
    __shared__ __align__(16) __bf16 Vlds[D_ * KVBLK];    // [128 d][64 k], 16 KB
    __shared__ __align__(16) __bf16 Plds[4 * 16 * KVBLK];// per-wave [16 q][64 k], 8 KB

    const int tid  = threadIdx.x;
    const int lane = tid & 63;
    const int w    = tid >> 6;
    const int lr   = lane & 15;   // MFMA row/col lane
    const int lg   = lane >> 4;   // 16-lane group 0..3

    const int qt = blockIdx.x;
    const int h  = blockIdx.y;
    const int b  = blockIdx.z;
    const int q0w = qt * QBLK + w * 16;

    const float scale_l2e = 0.08838834764831845f * 1.4426950408889634f; // 1/sqrt(128)*log2(e)

    // ---- Q fragments (pre-scaled -> scores land in log2 domain), q-row = lr ----
    bf16x8 qf[4];
    {
        const float* qsrc = Q + (((size_t)b*H_ + h)*SQ_ + q0w + lr)*(size_t)D_ + lg*8;
        #pragma unroll
        for (int c = 0; c < 4; ++c) {
            f32x4 a0 = *(const f32x4*)(qsrc + c*32);
            f32x4 a1 = *(const f32x4*)(qsrc + c*32 + 4);
            bf16x8 f;
            #pragma unroll
            for (int j = 0; j < 4; ++j) {
                f[j]   = f2bf(a0[j] * scale_l2e);
                f[j+4] = f2bf(a1[j] * scale_l2e);
            }
            qf[c] = f;
        }
    }

    f32x4 o[8];   // O^T orientation: o[dt][r] = O[q = q0w+lr][d = dt*16 + lg*4 + r]
    #pragma unroll
    for (int i = 0; i < 8; ++i) o[i] = (f32x4){0.f,0.f,0.f,0.f};
    float m_r = -1e30f, l_r = 0.f;

    const int ntiles = qt + 17;   // keys up to q0b+63+1024

    const size_t pk_base = (((size_t)b*HKV_ + (h>>2))*SP_)*(size_t)D_;
    const size_t kn_base = (((size_t)b*H_   + h     )*SQ_)*(size_t)D_;

    f32x4 kreg[4][2], vreg[2][4];

    // ---- prologue: tile 0 -> regs (tile 0 is always past) ----
    {
        const float* ks = PK + pk_base;
        #pragma unroll
        for (int i = 0; i < 4; ++i) {
            int idx = i*256 + tid, row = idx >> 4, c8 = idx & 15;
            kreg[i][0] = *(const f32x4*)(ks + row*D_ + c8*8);
            kreg[i][1] = *(const f32x4*)(ks + row*D_ + c8*8 + 4);
        }
        const float* vs = PV + pk_base;
        #pragma unroll
        for (int i = 0; i < 2; ++i) {
            int blk = i*256 + tid, bk = blk & 15, bd = blk >> 4;
            #pragma unroll
            for (int kk = 0; kk < 4; ++kk)
                vreg[i][kk] = *(const f32x4*)(vs + (4*bk+kk)*D_ + bd*4);
        }
    }

    for (int kt = 0; kt < ntiles; ++kt) {
        const int k0 = kt * KVBLK;
        __syncthreads();   // (A) prev compute done with LDS; prefetch loads drained (vmcnt0)

        // ---- staged regs -> LDS (fp32->bf16, swizzled) ----
        #pragma unroll
        for (int i = 0; i < 4; ++i) {
            int idx = i*256 + tid, row = idx >> 4, c8 = idx & 15;
            bf16x8 f;
            #pragma unroll
            for (int j = 0; j < 4; ++j) {
                f[j]   = f2bf(kreg[i][0][j]);
                f[j+4] = f2bf(kreg[i][1][j]);
            }
            int off = (row*256 + c8*16) ^ ((row & 7) << 4);
            *(bf16x8*)((char*)Klds + off) = f;
        }
        #pragma unroll
        for (int i = 0; i < 2; ++i) {
            int blk = i*256 + tid, bk = blk & 15, bd = blk >> 4;
            #pragma unroll
            for (int j = 0; j < 4; ++j) {
                int d = 4*bd + j;
                bf16x4 t;
                t[0]=f2bf(vreg[i][0][j]); t[1]=f2bf(vreg[i][1][j]);
                t[2]=f2bf(vreg[i][2][j]); t[3]=f2bf(vreg[i][3][j]);
                int off = (d*128 + bk*8) ^ ((d & 7) << 4);
                *(bf16x4*)((char*)Vlds + off) = t;
            }
        }
        __syncthreads();   // (B) LDS(kt) ready

        // ---- prefetch next tile -> regs (in flight during compute, drained at next (A)) ----
        if (kt + 1 < ntiles) {
            const int k1 = k0 + KVBLK;
            const float* ks = (k1 < SP_) ? PK + pk_base + (size_t)k1*D_
                                         : Kin + kn_base + (size_t)(k1 - SP_)*D_;
            #pragma unroll
            for (int i = 0; i < 4; ++i) {
                int idx = i*256 + tid, row = idx >> 4, c8 = idx & 15;
                kreg[i][0] = *(const f32x4*)(ks + row*D_ + c8*8);
                kreg[i][1] = *(const f32x4*)(ks + row*D_ + c8*8 + 4);
            }
            const float* vs = (k1 < SP_) ? PV + pk_base + (size_t)k1*D_
                                         : Vin + kn_base + (size_t)(k1 - SP_)*D_;
            #pragma unroll
            for (int i = 0; i < 2; ++i) {
                int blk = i*256 + tid, bk = blk & 15, bd = blk >> 4;
                #pragma unroll
                for (int kk = 0; kk < 4; ++kk)
                    vreg[i][kk] = *(const f32x4*)(vs + (4*bk+kk)*D_ + bd*4);
            }
        }

        // ---- QK^T swapped: S^T[k][q] = mfma(K, Q); lane holds k = n*16+lg*4+r, q = lr ----
        f32x4 s[4];
        #pragma unroll
        for (int n = 0; n < 4; ++n) s[n] = (f32x4){0.f,0.f,0.f,0.f};
        #pragma unroll
        for (int n = 0; n < 4; ++n) {
            #pragma unroll
            for (int c = 0; c < 4; ++c) {
                int off = ((n*16 + lr)*256 + c*64 + lg*16) ^ ((lr & 7) << 4);
                bf16x8 kf = *(const bf16x8*)((char*)Klds + off);
                s[n] = __builtin_amdgcn_mfma_f32_16x16x32_bf16(kf, qf[c], s[n], 0, 0, 0);
            }
        }

        // ---- causal mask (only the last tile needs it) ----
        float p[16];
        const bool needmask = (k0 + KVBLK - 1) > (q0w + SP_);
        if (needmask) {
            const int qv = q0w + lr + SP_;
            #pragma unroll
            for (int n = 0; n < 4; ++n)
                #pragma unroll
                for (int r = 0; r < 4; ++r) {
                    int kg = k0 + n*16 + lg*4 + r;
                    p[n*4+r] = (kg <= qv) ? s[n][r] : -1e30f;
                }
        } else {
            #pragma unroll
            for (int n = 0; n < 4; ++n)
                #pragma unroll
                for (int r = 0; r < 4; ++r) p[n*4+r] = s[n][r];
        }

        // ---- in-register online softmax (per q-row = lr; reduce over lg via 2 shfls) ----
        float mx = p[0];
        #pragma unroll
        for (int i = 1; i < 16; ++i) mx = fmaxf(mx, p[i]);
        mx = fmaxf(mx, __shfl_xor(mx, 16));
        mx = fmaxf(mx, __shfl_xor(mx, 32));
        float mnew  = fmaxf(m_r, mx);
        float alpha = exp2f(m_r - mnew);
        m_r = mnew;
        float psum = 0.f;
        #pragma unroll
        for (int i = 0; i < 16; ++i) { p[i] = exp2f(p[i] - mnew); psum += p[i]; }
        psum += __shfl_xor(psum, 16);
        psum += __shfl_xor(psum, 32);
        l_r = l_r * alpha + psum;
        #pragma unroll
        for (int dt = 0; dt < 8; ++dt) {
            o[dt][0] *= alpha; o[dt][1] *= alpha;
            o[dt][2] *= alpha; o[dt][3] *= alpha;
        }

        // ---- P -> per-wave LDS (bf16x4 stores, swizzled) ----
        char* Pw = (char*)Plds + w*2048;
        #pragma unroll
        for (int n = 0; n < 4; ++n) {
            bf16x4 t;
            t[0]=f2bf(p[n*4+0]); t[1]=f2bf(p[n*4+1]);
            t[2]=f2bf(p[n*4+2]); t[3]=f2bf(p[n*4+3]);
            int off = (lr*128 + n*32 + lg*8) ^ ((lr & 7) << 4);
            *(bf16x4*)(Pw + off) = t;
        }

        // ---- PV swapped: O^T[d][q] += mfma(V, P); no cross-lane for alpha/l ----
        #pragma unroll
        for (int kk = 0; kk < 2; ++kk) {
            int poff = (lr*128 + kk*64 + lg*16) ^ ((lr & 7) << 4);
            bf16x8 pa = *(const bf16x8*)(Pw + poff);
            #pragma unroll
            for (int dt = 0; dt < 8; ++dt) {
                int voff = ((dt*16 + lr)*128 + kk*64 + lg*16) ^ ((lr & 7) << 4);
                bf16x8 vf = *(const bf16x8*)((char*)Vlds + voff);
                o[dt] = __builtin_amdgcn_mfma_f32_16x16x32_bf16(vf, pa, o[dt], 0, 0, 0);
            }
        }
    }

    // ---- epilogue: lane owns row q0w+lr; float4 stores ----
    float inv = 1.0f / l_r;
    float* orow = Out + (((size_t)b*H_ + h)*SQ_ + q0w + lr)*(size_t)D_;
    #pragma unroll
    for (int dt = 0; dt < 8; ++dt) {
        f32x4 st;
        st[0]=o[dt][0]*inv; st[1]=o[dt][1]*inv;
        st[2]=o[dt][2]*inv; st[3]=o[dt][3]*inv;
        *(f32x4*)(orow + dt*16 + lg*4) = st;
    }
}

// present_key[b,g] = concat(past_key[b,g], K[b,4g]); same for value.
__global__ __launch_bounds__(256)
void copy_present_kernel(const float* __restrict__ Kin, const float* __restrict__ Vin,
                         const float* __restrict__ PK,  const float* __restrict__ PV,
                         float* __restrict__ opk, float* __restrict__ opv)
{
    const int n4 = B_*HKV_*SK_*(D_/4);         // 524288 float4 per output
    int idx = blockIdx.x*256 + threadIdx.x;    // 0 .. 2*n4-1
    bool isV = false;
    if (idx >= n4) { idx -= n4; isV = true; }
    int d4 = idx & 31;
    int s  = (idx >> 5) & (SK_-1);
    int bg = idx >> 16;                        // b*4+g
    int bb = bg >> 2, g = bg & 3;
    const float* srcp;
    if (s < SP_)
        srcp = (isV ? PV : PK) + (((size_t)bg)*SP_ + s)*(size_t)D_ + d4*4;
    else
        srcp = (isV ? Vin : Kin) + (((size_t)(bb*H_ + 4*g))*SQ_ + (s - SP_))*(size_t)D_ + d4*4;
    float4 v = *(const float4*)srcp;
    float* dstp = (isV ? opv : opk) + (size_t)idx*4;
    *(float4*)dstp = v;
}

extern "C" void kernel_launch(void* const* d_in, const int* in_sizes, int n_in,
                              void* d_out, int out_size, void* d_ws, size_t ws_size,
                              hipStream_t stream) {
    const float* Q   = (const float*)d_in[0];
    const float* K   = (const float*)d_in[1];
    const float* V   = (const float*)d_in[2];
    const float* PK  = (const float*)d_in[3];
    const float* PV  = (const float*)d_in[4];
    float* out = (float*)d_out;
    float* opk = out + (size_t)B_*H_*SQ_*D_;
    float* opv = opk + (size_t)B_*HKV_*SK_*D_;

    dim3 agrid(SQ_/QBLK, H_, B_);
    attn_fwd_kernel<<<agrid, 256, 0, stream>>>(Q, K, V, PK, PV, out);

    int copyblocks = (2 * B_*HKV_*SK_*(D_/4)) / 256;
    copy_present_kernel<<<copyblocks, 256, 0, stream>>>(K, V, PK, PV, opk, opv);
}